// Round 1
// baseline (1613.432 us; speedup 1.0000x reference)
//
#include <hip/hip_runtime.h>
#include <math.h>

#define Bn   4
#define Tn   2048
#define Dn   1024
#define Hn   4
#define DKn  128
#define DVn  256
#define KDn  512
#define VDn  1024
#define NROWS 8192

__device__ __forceinline__ float softplus_f(float x) {
    // stable: max(x,0) + log1p(exp(-|x|))
    return fmaxf(x, 0.0f) + log1pf(expf(-fabsf(x)));
}

// C[M x Ncols] = A[M x 1024] @ Bw[Ncols x 1024]^T
// MODE 0: plain. MODE 1: *= DK^-0.5 (q). MODE 2: gate transform -> E = exp(gk).
template<int MODE>
__global__ __launch_bounds__(256) void gemm_bt(
    const float* __restrict__ A, const float* __restrict__ Bw,
    float* __restrict__ C, int Ncols,
    const float* __restrict__ dt_bias,
    const float* __restrict__ A_log_base,
    const float* __restrict__ A_log_delta)
{
    __shared__ __align__(16) float As[16][68];
    __shared__ __align__(16) float Bs[16][68];
    const int tid = threadIdx.x;
    const int tx = tid & 15, ty = tid >> 4;
    const int row0 = blockIdx.y * 64;
    const int col0 = blockIdx.x * 64;
    const int lr  = tid >> 2;        // 0..63 (tile row)
    const int lkk = (tid & 3) << 2;  // 0,4,8,12 (k offset)
    const float* Ap = A  + (size_t)(row0 + lr) * Dn + lkk;
    const float* Bp = Bw + (size_t)(col0 + lr) * Dn + lkk;

    float acc[4][4] = {};
    for (int kt = 0; kt < Dn; kt += 16) {
        float4 a4 = *(const float4*)(Ap + kt);
        float4 b4 = *(const float4*)(Bp + kt);
        __syncthreads();
        As[lkk+0][lr] = a4.x; As[lkk+1][lr] = a4.y;
        As[lkk+2][lr] = a4.z; As[lkk+3][lr] = a4.w;
        Bs[lkk+0][lr] = b4.x; Bs[lkk+1][lr] = b4.y;
        Bs[lkk+2][lr] = b4.z; Bs[lkk+3][lr] = b4.w;
        __syncthreads();
        #pragma unroll
        for (int kk = 0; kk < 16; ++kk) {
            float4 av = *(const float4*)&As[kk][ty << 2];
            float4 bv = *(const float4*)&Bs[kk][tx << 2];
            float ar[4] = {av.x, av.y, av.z, av.w};
            float br[4] = {bv.x, bv.y, bv.z, bv.w};
            #pragma unroll
            for (int i = 0; i < 4; ++i)
                #pragma unroll
                for (int j = 0; j < 4; ++j)
                    acc[i][j] += ar[i] * br[j];
        }
    }

    if (MODE != 2) {
        const float scale = (MODE == 1) ? 0.08838834764831845f : 1.0f; // DK^-0.5
        #pragma unroll
        for (int i = 0; i < 4; ++i) {
            float4 o4 = make_float4(acc[i][0]*scale, acc[i][1]*scale,
                                    acc[i][2]*scale, acc[i][3]*scale);
            *(float4*)&C[(size_t)(row0 + (ty<<2) + i) * Ncols + col0 + (tx<<2)] = o4;
        }
    } else {
        // A_log[h] = base + cum[h]; cum = {0, cumsum(softplus(delta))}
        const float base = A_log_base[0];
        const float s0 = softplus_f(A_log_delta[0]);
        const float s1 = softplus_f(A_log_delta[1]);
        const float s2 = softplus_f(A_log_delta[2]);
        const float cum[4] = {0.f, s0, s0 + s1, s0 + s1 + s2};
        const float mg = cum[3] * (1.0f / 3.0f);
        const int colb = col0 + (tx << 2);   // 0..511 ; h uniform over 4 cols
        const int h = colb >> 7;
        float alpha = (float)(3 - h) * (1.0f / 3.0f)
                    + (cum[h] - (float)h * mg) * (1.0f / 6.2383246250395075f);
        alpha = fminf(fmaxf(alpha, 0.0f), 1.0f);
        const float expA = expf(base + cum[h]);
        const float4 db = *(const float4*)&dt_bias[colb];
        #pragma unroll
        for (int i = 0; i < 4; ++i) {
            const int row = row0 + (ty << 2) + i;
            const int t = row & (Tn - 1);
            const float pf = expf(-alpha * logf((float)(t + 1))); // pos^-alpha
            float4 e4;
            e4.x = expf(-expA * softplus_f(acc[i][0] + db.x) * pf);
            e4.y = expf(-expA * softplus_f(acc[i][1] + db.y) * pf);
            e4.z = expf(-expA * softplus_f(acc[i][2] + db.z) * pf);
            e4.w = expf(-expA * softplus_f(acc[i][3] + db.w) * pf);
            *(float4*)&C[(size_t)row * Ncols + colb] = e4;
        }
    }
}

// Sequential GLA recurrence. Grid: (dvblk=16, h=4, b=4). Block: 256 threads.
// Thread (part = tid&15, dvi = tid>>4) owns S[dk in {part*4..+4, 64+part*4..+4}][dv=dvblk*16+dvi].
__global__ __launch_bounds__(256) void gla_rec(
    const float* __restrict__ q, const float* __restrict__ k,
    const float* __restrict__ E, const float* __restrict__ v,
    float* __restrict__ o)
{
    __shared__ __align__(16) float lq[32][128];
    __shared__ __align__(16) float lk[32][128];
    __shared__ __align__(16) float lE[32][128];
    __shared__ __align__(16) float lv[32][16];
    __shared__ __align__(16) float lo[32][16];

    const int tid = threadIdx.x;
    const int part = tid & 15, dvi = tid >> 4;
    const int b = blockIdx.z, h = blockIdx.y, dvb = blockIdx.x;
    const int dkA = part << 2;          // part*4
    const int dkB = 64 + (part << 2);   // 64 + part*4
    const size_t qkbase = (size_t)(b * Tn) * KDn + h * DKn;
    const size_t vbase  = (size_t)(b * Tn) * VDn + h * DVn + dvb * 16;

    float S[8] = {0.f,0.f,0.f,0.f,0.f,0.f,0.f,0.f};

    for (int c = 0; c < Tn / 32; ++c) {
        const int t0 = c * 32;
        // stage q,k,E: 32 timesteps x 128 dk
        #pragma unroll
        for (int i = tid; i < 32 * 32; i += 256) {
            const int tt = i >> 5, c4 = (i & 31) << 2;
            const size_t go = qkbase + (size_t)(t0 + tt) * KDn + c4;
            *(float4*)&lq[tt][c4] = *(const float4*)&q[go];
            *(float4*)&lk[tt][c4] = *(const float4*)&k[go];
            *(float4*)&lE[tt][c4] = *(const float4*)&E[go];
        }
        if (tid < 128) {
            const int tt = tid >> 2, c4 = (tid & 3) << 2;
            *(float4*)&lv[tt][c4] = *(const float4*)&v[vbase + (size_t)(t0 + tt) * VDn + c4];
        }
        __syncthreads();

        #pragma unroll 4
        for (int tt = 0; tt < 32; ++tt) {
            float4 kA = *(const float4*)&lk[tt][dkA];
            float4 kB = *(const float4*)&lk[tt][dkB];
            float4 eA = *(const float4*)&lE[tt][dkA];
            float4 eB = *(const float4*)&lE[tt][dkB];
            float4 qA = *(const float4*)&lq[tt][dkA];
            float4 qB = *(const float4*)&lq[tt][dkB];
            const float vv = lv[tt][dvi];

            S[0] = S[0]*eA.x + kA.x*vv;  S[1] = S[1]*eA.y + kA.y*vv;
            S[2] = S[2]*eA.z + kA.z*vv;  S[3] = S[3]*eA.w + kA.w*vv;
            S[4] = S[4]*eB.x + kB.x*vv;  S[5] = S[5]*eB.y + kB.y*vv;
            S[6] = S[6]*eB.z + kB.z*vv;  S[7] = S[7]*eB.w + kB.w*vv;

            float p = qA.x*S[0] + qA.y*S[1] + qA.z*S[2] + qA.w*S[3]
                    + qB.x*S[4] + qB.y*S[5] + qB.z*S[6] + qB.w*S[7];
            p += __shfl_xor(p, 1);
            p += __shfl_xor(p, 2);
            p += __shfl_xor(p, 4);
            p += __shfl_xor(p, 8);
            if (part == 0) lo[tt][dvi] = p;
        }
        __syncthreads();

        if (tid < 128) {
            const int tt = tid >> 2, c4 = (tid & 3) << 2;
            *(float4*)&o[vbase + (size_t)(t0 + tt) * VDn + c4] = *(const float4*)&lo[tt][c4];
        }
    }
}

// RMSNorm over dv (per b,t,h) + swish gate. One wave per (n,h). In-place safe.
__global__ __launch_bounds__(64) void rms_gate(
    const float* __restrict__ o, const float* __restrict__ g,
    const float* __restrict__ w, float* __restrict__ out)
{
    const int bid = blockIdx.x;     // n*H + h
    const int n = bid >> 2, h = bid & 3;
    const size_t base = (size_t)n * VDn + h * DVn;
    const int tid = threadIdx.x;

    float4 o4 = *(const float4*)&o[base + (tid << 2)];
    float ss = o4.x*o4.x + o4.y*o4.y + o4.z*o4.z + o4.w*o4.w;
    #pragma unroll
    for (int m = 1; m < 64; m <<= 1) ss += __shfl_xor(ss, m);
    const float r = rsqrtf(ss * (1.0f / DVn) + 1e-5f);

    float4 g4 = *(const float4*)&g[base + (tid << 2)];
    float4 w4 = *(const float4*)&w[h * DVn + (tid << 2)];
    float4 r4;
    r4.x = o4.x * r * w4.x * (g4.x / (1.0f + expf(-g4.x)));
    r4.y = o4.y * r * w4.y * (g4.y / (1.0f + expf(-g4.y)));
    r4.z = o4.z * r * w4.z * (g4.z / (1.0f + expf(-g4.z)));
    r4.w = o4.w * r * w4.w * (g4.w / (1.0f + expf(-g4.w)));
    *(float4*)&out[base + (tid << 2)] = r4;
}

extern "C" void kernel_launch(void* const* d_in, const int* in_sizes, int n_in,
                              void* d_out, int out_size, void* d_ws, size_t ws_size,
                              hipStream_t stream) {
    const float* hs          = (const float*)d_in[0];
    const float* Wq          = (const float*)d_in[1];
    const float* Wk          = (const float*)d_in[2];
    const float* Wv          = (const float*)d_in[3];
    const float* Wg          = (const float*)d_in[4];
    const float* Wa          = (const float*)d_in[5];
    const float* Wo          = (const float*)d_in[6];
    const float* A_log_base  = (const float*)d_in[7];
    const float* A_log_delta = (const float*)d_in[8];
    const float* dt_bias     = (const float*)d_in[9];
    const float* gnw         = (const float*)d_in[10];
    float* out = (float*)d_out;

    char* ws = (char*)d_ws;
    float* qb = (float*)(ws);                         // 16 MB  [8192 x 512]
    float* kb = (float*)(ws + ((size_t)16 << 20));    // 16 MB
    float* Eb = (float*)(ws + ((size_t)32 << 20));    // 16 MB
    float* vb = (float*)(ws + ((size_t)48 << 20));    // 32 MB  [8192 x 1024]
    float* gb = (float*)(ws + ((size_t)80 << 20));    // 32 MB
    float* ob = (float*)(ws + ((size_t)112 << 20));   // 32 MB

    dim3 blk(256);
    dim3 g512(KDn / 64, NROWS / 64);    // (8, 128)
    dim3 g1024(VDn / 64, NROWS / 64);   // (16, 128)

    gemm_bt<1><<<g512,  blk, 0, stream>>>(hs, Wq, qb, KDn, nullptr, nullptr, nullptr);
    gemm_bt<0><<<g512,  blk, 0, stream>>>(hs, Wk, kb, KDn, nullptr, nullptr, nullptr);
    gemm_bt<0><<<g1024, blk, 0, stream>>>(hs, Wv, vb, VDn, nullptr, nullptr, nullptr);
    gemm_bt<0><<<g1024, blk, 0, stream>>>(hs, Wg, gb, VDn, nullptr, nullptr, nullptr);
    gemm_bt<2><<<g512,  blk, 0, stream>>>(hs, Wa, Eb, KDn, dt_bias, A_log_base, A_log_delta);

    gla_rec<<<dim3(16, Hn, Bn), blk, 0, stream>>>(qb, kb, Eb, vb, ob);

    rms_gate<<<dim3(NROWS * Hn), dim3(64), 0, stream>>>(ob, gb, gnw, ob);

    gemm_bt<0><<<g1024, blk, 0, stream>>>(ob, Wo, out, VDn, nullptr, nullptr, nullptr);
}

// Round 2
// 572.707 us; speedup vs baseline: 2.8172x; 2.8172x over previous
//
#include <hip/hip_runtime.h>
#include <math.h>

#define Bn   4
#define Tn   2048
#define Dn   1024
#define Hn   4
#define DKn  128
#define DVn  256
#define KDn  512
#define VDn  1024
#define NROWS 8192
#define NC   16
#define CL   128

using bf16x8 = __attribute__((ext_vector_type(8))) short;
using f32x4  = __attribute__((ext_vector_type(4))) float;

__device__ __forceinline__ float softplus_f(float x) {
    return fmaxf(x, 0.0f) + log1pf(expf(-fabsf(x)));
}
__device__ __forceinline__ ushort f2bf(float f) {
    unsigned u = __float_as_uint(f);
    u = (u + 0x7fffu + ((u >> 16) & 1u)) >> 16;
    return (ushort)u;
}

// ---------- cast fp32 -> bf16 (vectorized) ----------
__global__ __launch_bounds__(256) void cast_f2b(const float* __restrict__ x,
                                                ushort* __restrict__ y, int n4) {
    int i = blockIdx.x * 256 + threadIdx.x;
    if (i < n4) {
        float4 v = *(const float4*)&x[i * 4];
        ushort4 o;
        o.x = f2bf(v.x); o.y = f2bf(v.y); o.z = f2bf(v.z); o.w = f2bf(v.w);
        *(ushort4*)&y[i * 4] = o;
    }
}

// ---------- fp32 GEMM for the decay-gate projection (kept from R1, MODE 2) ----------
template<int MODE>
__global__ __launch_bounds__(256) void gemm_bt(
    const float* __restrict__ A, const float* __restrict__ Bw,
    float* __restrict__ C, int Ncols,
    const float* __restrict__ dt_bias,
    const float* __restrict__ A_log_base,
    const float* __restrict__ A_log_delta)
{
    __shared__ __align__(16) float As[16][68];
    __shared__ __align__(16) float Bs[16][68];
    const int tid = threadIdx.x;
    const int tx = tid & 15, ty = tid >> 4;
    const int row0 = blockIdx.y * 64;
    const int col0 = blockIdx.x * 64;
    const int lr  = tid >> 2;
    const int lkk = (tid & 3) << 2;
    const float* Ap = A  + (size_t)(row0 + lr) * Dn + lkk;
    const float* Bp = Bw + (size_t)(col0 + lr) * Dn + lkk;

    float acc[4][4] = {};
    for (int kt = 0; kt < Dn; kt += 16) {
        float4 a4 = *(const float4*)(Ap + kt);
        float4 b4 = *(const float4*)(Bp + kt);
        __syncthreads();
        As[lkk+0][lr] = a4.x; As[lkk+1][lr] = a4.y;
        As[lkk+2][lr] = a4.z; As[lkk+3][lr] = a4.w;
        Bs[lkk+0][lr] = b4.x; Bs[lkk+1][lr] = b4.y;
        Bs[lkk+2][lr] = b4.z; Bs[lkk+3][lr] = b4.w;
        __syncthreads();
        #pragma unroll
        for (int kk = 0; kk < 16; ++kk) {
            float4 av = *(const float4*)&As[kk][ty << 2];
            float4 bv = *(const float4*)&Bs[kk][tx << 2];
            float ar[4] = {av.x, av.y, av.z, av.w};
            float br[4] = {bv.x, bv.y, bv.z, bv.w};
            #pragma unroll
            for (int i = 0; i < 4; ++i)
                #pragma unroll
                for (int j = 0; j < 4; ++j)
                    acc[i][j] += ar[i] * br[j];
        }
    }
    {
        const float base = A_log_base[0];
        const float s0 = softplus_f(A_log_delta[0]);
        const float s1 = softplus_f(A_log_delta[1]);
        const float s2 = softplus_f(A_log_delta[2]);
        const float cum[4] = {0.f, s0, s0 + s1, s0 + s1 + s2};
        const float mg = cum[3] * (1.0f / 3.0f);
        const int colb = col0 + (tx << 2);
        const int h = colb >> 7;
        float alpha = (float)(3 - h) * (1.0f / 3.0f)
                    + (cum[h] - (float)h * mg) * (1.0f / 6.2383246250395075f);
        alpha = fminf(fmaxf(alpha, 0.0f), 1.0f);
        const float expA = expf(base + cum[h]);
        const float4 db = *(const float4*)&dt_bias[colb];
        #pragma unroll
        for (int i = 0; i < 4; ++i) {
            const int row = row0 + (ty << 2) + i;
            const int t = row & (Tn - 1);
            const float pf = expf(-alpha * logf((float)(t + 1)));
            float4 e4;
            e4.x = expf(-expA * softplus_f(acc[i][0] + db.x) * pf);
            e4.y = expf(-expA * softplus_f(acc[i][1] + db.y) * pf);
            e4.z = expf(-expA * softplus_f(acc[i][2] + db.z) * pf);
            e4.w = expf(-expA * softplus_f(acc[i][3] + db.w) * pf);
            *(float4*)&C[(size_t)row * Ncols + colb] = e4;
        }
    }
}

// ---------- bf16 MFMA GEMM: C[M x N] = A[M x 1024] @ Bw[N x 1024]^T (fp32 out) ----------
// MODE 0: plain. MODE 1: scale cols < 512 by DK^-0.5 (fused q-scale in qk GEMM).
template<int MODE>
__global__ __launch_bounds__(256) void mm_bf16(const ushort* __restrict__ A,
    const ushort* __restrict__ Bw, float* __restrict__ C, int Ncols)
{
    __shared__ __align__(16) ushort As[4][128][8];
    __shared__ __align__(16) ushort Bs[4][128][8];
    const int tid = threadIdx.x;
    const int lane = tid & 63, w = tid >> 6;
    const int l15 = lane & 15, lg = lane >> 4;
    const int wr = (w >> 1) << 6, wc = (w & 1) << 6;
    const int row0 = blockIdx.y << 7, col0 = blockIdx.x << 7;
    const int r0 = tid & 127, gA = tid >> 7;   // gA in {0,1}
    const ushort* Apr = A  + (size_t)(row0 + r0) * Dn;
    const ushort* Bpr = Bw + (size_t)(col0 + r0) * Dn;

    f32x4 acc[4][4];
    #pragma unroll
    for (int m = 0; m < 4; ++m)
        #pragma unroll
        for (int n = 0; n < 4; ++n)
            acc[m][n] = (f32x4){0.f, 0.f, 0.f, 0.f};

    for (int kt = 0; kt < Dn; kt += 32) {
        int4 a0 = *(const int4*)(Apr + kt + gA * 8);
        int4 a1 = *(const int4*)(Apr + kt + (gA + 2) * 8);
        int4 b0 = *(const int4*)(Bpr + kt + gA * 8);
        int4 b1 = *(const int4*)(Bpr + kt + (gA + 2) * 8);
        __syncthreads();
        *(int4*)&As[gA][r0][0]     = a0;
        *(int4*)&As[gA + 2][r0][0] = a1;
        *(int4*)&Bs[gA][r0][0]     = b0;
        *(int4*)&Bs[gA + 2][r0][0] = b1;
        __syncthreads();
        bf16x8 af[4], bv[4];
        #pragma unroll
        for (int m = 0; m < 4; ++m) af[m] = *(const bf16x8*)&As[lg][wr + m*16 + l15][0];
        #pragma unroll
        for (int n = 0; n < 4; ++n) bv[n] = *(const bf16x8*)&Bs[lg][wc + n*16 + l15][0];
        #pragma unroll
        for (int m = 0; m < 4; ++m)
            #pragma unroll
            for (int n = 0; n < 4; ++n)
                acc[m][n] = __builtin_amdgcn_mfma_f32_16x16x32_bf16(af[m], bv[n], acc[m][n], 0, 0, 0);
    }
    #pragma unroll
    for (int m = 0; m < 4; ++m) {
        const int row = row0 + wr + m * 16 + lg * 4;
        #pragma unroll
        for (int n = 0; n < 4; ++n) {
            const int col = col0 + wc + n * 16 + l15;
            const float s = (MODE == 1 && (col0 + wc + n * 16) < KDn) ? 0.08838834764831845f : 1.0f;
            #pragma unroll
            for (int r = 0; r < 4; ++r)
                C[(size_t)(row + r) * Ncols + col] = acc[m][n][r] * s;
        }
    }
}

// ---------- chunked GLA recurrence ----------
// Thread (part=tid&15, dvi=tid>>4) owns dk {part*4..+4, 64+part*4..+4} x dv {dvb*64+dvi*4..+4}.
// qk: [8192][1024] (q cols 0-511 pre-scaled, k cols 512-1023). vg: [8192][2048] (v cols 0-1023).

__global__ __launch_bounds__(256) void gla_state(const float* __restrict__ qk,
    const float* __restrict__ E, const float* __restrict__ vg, float* __restrict__ Sl)
{
    const int tid = threadIdx.x;
    const int part = tid & 15, dvi = tid >> 4;
    const int dvb = blockIdx.x, bh = blockIdx.y, c = blockIdx.z;
    const int b = bh >> 2, h = bh & 3;
    const int t0 = c * CL;
    const float* kp = qk + (size_t)(b * Tn + t0) * 1024 + 512 + h * DKn + part * 4;
    const float* Ep = E  + (size_t)(b * Tn + t0) * KDn  + h * DKn + part * 4;
    const float* vp = vg + (size_t)(b * Tn + t0) * 2048 + h * DVn + dvb * 64 + dvi * 4;

    float S[8][4];
    #pragma unroll
    for (int i = 0; i < 8; ++i)
        #pragma unroll
        for (int j = 0; j < 4; ++j) S[i][j] = 0.f;

    #pragma unroll 2
    for (int t = 0; t < CL; ++t) {
        float4 kA = *(const float4*)kp;
        float4 kB = *(const float4*)(kp + 64);
        float4 eA = *(const float4*)Ep;
        float4 eB = *(const float4*)(Ep + 64);
        float4 vv = *(const float4*)vp;
        kp += 1024; Ep += KDn; vp += 2048;
        float kr[8] = {kA.x,kA.y,kA.z,kA.w,kB.x,kB.y,kB.z,kB.w};
        float er[8] = {eA.x,eA.y,eA.z,eA.w,eB.x,eB.y,eB.z,eB.w};
        float vr[4] = {vv.x,vv.y,vv.z,vv.w};
        #pragma unroll
        for (int i = 0; i < 8; ++i)
            #pragma unroll
            for (int j = 0; j < 4; ++j)
                S[i][j] = S[i][j] * er[i] + kr[i] * vr[j];
    }
    float* sp = Sl + (((size_t)c * 16 + bh) << 15);
    #pragma unroll
    for (int i = 0; i < 8; ++i) {
        const int dk = (i < 4) ? part * 4 + i : 64 + part * 4 + (i - 4);
        *(float4*)&sp[dk * DVn + dvb * 64 + dvi * 4] = make_float4(S[i][0], S[i][1], S[i][2], S[i][3]);
    }
}

// per-chunk per-dk total decay product D_c[dk] = prod_t E[t,dk]
__global__ void decay_prod(const float* __restrict__ E, float* __restrict__ Dc) {
    const int dk = threadIdx.x;           // 0..127
    const int c = blockIdx.x, bh = blockIdx.y;
    const int b = bh >> 2, h = bh & 3;
    const float* Ep = E + (size_t)(b * Tn + c * CL) * KDn + h * DKn + dk;
    float p = 1.f;
    for (int t = 0; t < CL; ++t) { p *= *Ep; Ep += KDn; }
    Dc[(c * 16 + bh) * DKn + dk] = p;
}

// sequential chunk combine: overwrite Sl[c] with the START state of chunk c
__global__ __launch_bounds__(256) void combine(float* __restrict__ Sl,
                                               const float* __restrict__ Dc) {
    const int bh = blockIdx.y;
    const int e = blockIdx.x * 256 + threadIdx.x;   // dk*256 + dv
    const int dk = e >> 8;
    float s = 0.f;
    for (int c = 0; c < NC; ++c) {
        float* p = Sl + (((size_t)c * 16 + bh) << 15) + e;
        const float local = *p;
        *p = s;
        s = s * Dc[(c * 16 + bh) * DKn + dk] + local;
    }
}

__global__ __launch_bounds__(256) void gla_out(const float* __restrict__ qk,
    const float* __restrict__ E, const float* __restrict__ vg,
    const float* __restrict__ Sl, float* __restrict__ o)
{
    const int tid = threadIdx.x;
    const int part = tid & 15, dvi = tid >> 4;
    const int dvb = blockIdx.x, bh = blockIdx.y, c = blockIdx.z;
    const int b = bh >> 2, h = bh & 3;
    const int t0 = c * CL;
    const float* qp = qk + (size_t)(b * Tn + t0) * 1024 + h * DKn + part * 4;
    const float* Ep = E  + (size_t)(b * Tn + t0) * KDn  + h * DKn + part * 4;
    const float* vp = vg + (size_t)(b * Tn + t0) * 2048 + h * DVn + dvb * 64 + dvi * 4;
    float* op = o + (size_t)(b * Tn + t0) * VDn + h * DVn + dvb * 64 + dvi * 4;

    const float* sp = Sl + (((size_t)c * 16 + bh) << 15);
    float S[8][4];
    #pragma unroll
    for (int i = 0; i < 8; ++i) {
        const int dk = (i < 4) ? part * 4 + i : 64 + part * 4 + (i - 4);
        float4 s4 = *(const float4*)&sp[dk * DVn + dvb * 64 + dvi * 4];
        S[i][0] = s4.x; S[i][1] = s4.y; S[i][2] = s4.z; S[i][3] = s4.w;
    }

    for (int t = 0; t < CL; ++t) {
        float4 qA = *(const float4*)qp;
        float4 qB = *(const float4*)(qp + 64);
        float4 kA = *(const float4*)(qp + 512);
        float4 kB = *(const float4*)(qp + 576);
        float4 eA = *(const float4*)Ep;
        float4 eB = *(const float4*)(Ep + 64);
        float4 vv = *(const float4*)vp;
        qp += 1024; Ep += KDn; vp += 2048;
        float qr[8] = {qA.x,qA.y,qA.z,qA.w,qB.x,qB.y,qB.z,qB.w};
        float kr[8] = {kA.x,kA.y,kA.z,kA.w,kB.x,kB.y,kB.z,kB.w};
        float er[8] = {eA.x,eA.y,eA.z,eA.w,eB.x,eB.y,eB.z,eB.w};
        float vr[4] = {vv.x,vv.y,vv.z,vv.w};
        float p[4] = {0.f, 0.f, 0.f, 0.f};
        #pragma unroll
        for (int i = 0; i < 8; ++i) {
            #pragma unroll
            for (int j = 0; j < 4; ++j) {
                S[i][j] = S[i][j] * er[i] + kr[i] * vr[j];
                p[j] += qr[i] * S[i][j];
            }
        }
        #pragma unroll
        for (int j = 0; j < 4; ++j) {
            p[j] += __shfl_xor(p[j], 1);
            p[j] += __shfl_xor(p[j], 2);
            p[j] += __shfl_xor(p[j], 4);
            p[j] += __shfl_xor(p[j], 8);
        }
        if (part == 0) *(float4*)op = make_float4(p[0], p[1], p[2], p[3]);
        op += VDn;
    }
}

// ---------- RMSNorm + swish gate, emits bf16 for the output GEMM ----------
__global__ __launch_bounds__(256) void rms_gate(const float* __restrict__ o,
    const float* __restrict__ vg, const float* __restrict__ wt,
    ushort* __restrict__ obf)
{
    const int tid = threadIdx.x;
    const int w = tid >> 6, lane = tid & 63;
    const int row = blockIdx.x * 4 + w;     // n*H + h
    const int n = row >> 2, h = row & 3;
    const size_t ob_base = (size_t)n * VDn + h * DVn + lane * 4;
    const size_t g_base  = (size_t)n * 2048 + 1024 + h * DVn + lane * 4;

    float4 o4 = *(const float4*)&o[ob_base];
    float ss = o4.x*o4.x + o4.y*o4.y + o4.z*o4.z + o4.w*o4.w;
    #pragma unroll
    for (int m = 1; m < 64; m <<= 1) ss += __shfl_xor(ss, m);
    const float r = rsqrtf(ss * (1.0f / DVn) + 1e-5f);

    float4 g4 = *(const float4*)&vg[g_base];
    float4 w4 = *(const float4*)&wt[h * DVn + lane * 4];
    ushort4 u;
    u.x = f2bf(o4.x * r * w4.x * (g4.x / (1.0f + expf(-g4.x))));
    u.y = f2bf(o4.y * r * w4.y * (g4.y / (1.0f + expf(-g4.y))));
    u.z = f2bf(o4.z * r * w4.z * (g4.z / (1.0f + expf(-g4.z))));
    u.w = f2bf(o4.w * r * w4.w * (g4.w / (1.0f + expf(-g4.w))));
    *(ushort4*)&obf[ob_base] = u;
}

extern "C" void kernel_launch(void* const* d_in, const int* in_sizes, int n_in,
                              void* d_out, int out_size, void* d_ws, size_t ws_size,
                              hipStream_t stream) {
    const float* hs          = (const float*)d_in[0];
    const float* Wq          = (const float*)d_in[1];
    const float* Wk          = (const float*)d_in[2];
    const float* Wv          = (const float*)d_in[3];
    const float* Wg          = (const float*)d_in[4];
    const float* Wa          = (const float*)d_in[5];
    const float* Wo          = (const float*)d_in[6];
    const float* A_log_base  = (const float*)d_in[7];
    const float* A_log_delta = (const float*)d_in[8];
    const float* dt_bias     = (const float*)d_in[9];
    const float* gnw         = (const float*)d_in[10];
    float* out = (float*)d_out;

    char* ws = (char*)d_ws;
    float*  qkb  = (float*)(ws);                          //  32 MB [8192][1024] q|k
    float*  vgb  = (float*)(ws + ((size_t)32  << 20));    //  64 MB [8192][2048] v|g
    float*  Eb   = (float*)(ws + ((size_t)96  << 20));    //  16 MB [8192][512]
    float*  ob   = (float*)(ws + ((size_t)112 << 20));    //  32 MB [8192][1024]
    float*  Sl   = (float*)(ws + ((size_t)144 << 20));    //  32 MB [16][16][128][256]
    float*  Dc   = (float*)(ws + ((size_t)176 << 20));    // 128 KB [16][16][128]
    ushort* hsb  = (ushort*)(ws + ((size_t)177 << 20));   //  16 MB [8192][1024] bf16
    ushort* Wqkb = (ushort*)(ws + ((size_t)193 << 20));   //   2 MB [1024][1024] bf16
    ushort* Wvgb = (ushort*)(ws + ((size_t)195 << 20));   //   4 MB [2048][1024] bf16
    ushort* Wob  = (ushort*)(ws + ((size_t)199 << 20));   //   2 MB [1024][1024] bf16
    ushort* obf  = (ushort*)qkb;                          // reuse: qk dead after gla_out

    // casts
    cast_f2b<<<NROWS * Dn / 4 / 256, 256, 0, stream>>>(hs, hsb, NROWS * Dn / 4);
    cast_f2b<<<512,  256, 0, stream>>>(Wq, Wqkb,                 KDn * Dn / 4);
    cast_f2b<<<512,  256, 0, stream>>>(Wk, Wqkb + KDn * Dn,      KDn * Dn / 4);
    cast_f2b<<<1024, 256, 0, stream>>>(Wv, Wvgb,                 VDn * Dn / 4);
    cast_f2b<<<1024, 256, 0, stream>>>(Wg, Wvgb + VDn * Dn,      VDn * Dn / 4);
    cast_f2b<<<1024, 256, 0, stream>>>(Wo, Wob,                  VDn * Dn / 4);

    // projections
    mm_bf16<1><<<dim3(8,  64), 256, 0, stream>>>(hsb, Wqkb, qkb, 1024);
    mm_bf16<0><<<dim3(16, 64), 256, 0, stream>>>(hsb, Wvgb, vgb, 2048);
    gemm_bt<2><<<dim3(8, 128), 256, 0, stream>>>(hs, Wa, Eb, KDn, dt_bias, A_log_base, A_log_delta);

    // chunked recurrence
    gla_state<<<dim3(4, 16, NC), 256, 0, stream>>>(qkb, Eb, vgb, Sl);
    decay_prod<<<dim3(NC, 16), 128, 0, stream>>>(Eb, Dc);
    combine<<<dim3(128, 16), 256, 0, stream>>>(Sl, Dc);
    gla_out<<<dim3(4, 16, NC), 256, 0, stream>>>(qkb, Eb, vgb, Sl, ob);

    // epilogue
    rms_gate<<<NROWS * Hn / 4, 256, 0, stream>>>(ob, vgb, gnw, obf);
    mm_bf16<0><<<dim3(8, 64), 256, 0, stream>>>(obf, Wob, out, 1024);
}

// Round 3
// 540.454 us; speedup vs baseline: 2.9853x; 1.0597x over previous
//
#include <hip/hip_runtime.h>
#include <math.h>

#define Bn   4
#define Tn   2048
#define Dn   1024
#define Hn   4
#define DKn  128
#define DVn  256
#define KDn  512
#define VDn  1024
#define NROWS 8192
#define NC   16
#define CL   128

using bf16x8 = __attribute__((ext_vector_type(8))) short;
using f32x4  = __attribute__((ext_vector_type(4))) float;

__device__ __forceinline__ float softplus_f(float x) {
    return fmaxf(x, 0.0f) + log1pf(expf(-fabsf(x)));
}
__device__ __forceinline__ ushort f2bf(float f) {
    unsigned u = __float_as_uint(f);
    u = (u + 0x7fffu + ((u >> 16) & 1u)) >> 16;
    return (ushort)u;
}
__device__ __forceinline__ void gload16(const void* g, void* l) {
    __builtin_amdgcn_global_load_lds(
        (const __attribute__((address_space(1))) unsigned*)g,
        (__attribute__((address_space(3))) unsigned*)l, 16, 0, 0);
}
// full-sum butterfly over each aligned 16-lane row, pure VALU (DPP)
__device__ __forceinline__ float dpp_red16(float p) {
    p += __int_as_float(__builtin_amdgcn_mov_dpp(__float_as_int(p), 0xB1,  0xF, 0xF, true)); // xor1
    p += __int_as_float(__builtin_amdgcn_mov_dpp(__float_as_int(p), 0x4E,  0xF, 0xF, true)); // xor2
    p += __int_as_float(__builtin_amdgcn_mov_dpp(__float_as_int(p), 0x124, 0xF, 0xF, true)); // ror4
    p += __int_as_float(__builtin_amdgcn_mov_dpp(__float_as_int(p), 0x128, 0xF, 0xF, true)); // ror8
    return p;
}

// ---------- cast fp32 -> bf16 ----------
__global__ __launch_bounds__(256) void cast_f2b(const float* __restrict__ x,
                                                ushort* __restrict__ y, int n4) {
    int i = blockIdx.x * 256 + threadIdx.x;
    if (i < n4) {
        float4 v = *(const float4*)&x[i * 4];
        ushort4 o;
        o.x = f2bf(v.x); o.y = f2bf(v.y); o.z = f2bf(v.z); o.w = f2bf(v.w);
        *(ushort4*)&y[i * 4] = o;
    }
}

// ---------- bf16 MFMA GEMM, global_load_lds staging (m97 structure) ----------
// C[M x Ncols] = A[M x 1024] @ Bw[Ncols x 1024]^T, fp32 out.
// MODE 1: scale cols < 512 by DK^-0.5 (fused q-scale).
template<int MODE>
__global__ __launch_bounds__(256) void mm_bf16(const ushort* __restrict__ A,
    const ushort* __restrict__ Bw, float* __restrict__ C, int Ncols)
{
    __shared__ __align__(16) ushort As[4][128][8];   // [kgroup(8 bf16)][row][8]
    __shared__ __align__(16) ushort Bs[4][128][8];
    const int tid = threadIdx.x;
    const int lane = tid & 63, w = tid >> 6;
    const int l15 = lane & 15, lg = lane >> 4;
    const int wr = (w >> 1) << 6, wc = (w & 1) << 6;
    const int row0 = blockIdx.y << 7, col0 = blockIdx.x << 7;

    // wave w stages k-group g=w, halves 0/1, for both A and B
    const ushort* Ag0 = A  + (size_t)(row0 + lane) * Dn + w * 8;
    const ushort* Ag1 = A  + (size_t)(row0 + 64 + lane) * Dn + w * 8;
    const ushort* Bg0 = Bw + (size_t)(col0 + lane) * Dn + w * 8;
    const ushort* Bg1 = Bw + (size_t)(col0 + 64 + lane) * Dn + w * 8;
    ushort* lA0 = &As[w][0][0];
    ushort* lA1 = &As[w][64][0];
    ushort* lB0 = &Bs[w][0][0];
    ushort* lB1 = &Bs[w][64][0];

    f32x4 acc[4][4];
    #pragma unroll
    for (int m = 0; m < 4; ++m)
        #pragma unroll
        for (int n = 0; n < 4; ++n)
            acc[m][n] = (f32x4){0.f, 0.f, 0.f, 0.f};

    for (int kt = 0; kt < Dn; kt += 32) {
        __syncthreads();                       // prior tile's ds_reads done
        gload16(Ag0 + kt, lA0);
        gload16(Ag1 + kt, lA1);
        gload16(Bg0 + kt, lB0);
        gload16(Bg1 + kt, lB1);
        __syncthreads();                       // vmcnt(0) drain before reads
        bf16x8 af[4], bv[4];
        #pragma unroll
        for (int m = 0; m < 4; ++m) af[m] = *(const bf16x8*)&As[lg][wr + m*16 + l15][0];
        #pragma unroll
        for (int n = 0; n < 4; ++n) bv[n] = *(const bf16x8*)&Bs[lg][wc + n*16 + l15][0];
        #pragma unroll
        for (int m = 0; m < 4; ++m)
            #pragma unroll
            for (int n = 0; n < 4; ++n)
                acc[m][n] = __builtin_amdgcn_mfma_f32_16x16x32_bf16(af[m], bv[n], acc[m][n], 0, 0, 0);
    }
    #pragma unroll
    for (int m = 0; m < 4; ++m) {
        const int row = row0 + wr + m * 16 + lg * 4;
        #pragma unroll
        for (int n = 0; n < 4; ++n) {
            const int col = col0 + wc + n * 16 + l15;
            const float s = (MODE == 1 && (col0 + wc + n * 16) < KDn) ? 0.08838834764831845f : 1.0f;
            #pragma unroll
            for (int r = 0; r < 4; ++r)
                C[(size_t)(row + r) * Ncols + col] = acc[m][n][r] * s;
        }
    }
}

// ---------- decay gate: E = exp(-exp(A_log[h]) * softplus(a+dt_bias) * pos^-alpha) ----------
__global__ __launch_bounds__(256) void gate_e(const float* __restrict__ qka,
    const float* __restrict__ dt_bias, const float* __restrict__ A_log_base,
    const float* __restrict__ A_log_delta, float* __restrict__ Eo)
{
    const int i4 = blockIdx.x * 256 + threadIdx.x;   // float4 idx over [8192][512]
    const int row = i4 >> 7;
    const int col = (i4 & 127) << 2;
    const int h = col >> 7;
    const float base = A_log_base[0];
    const float s0 = softplus_f(A_log_delta[0]);
    const float s1 = softplus_f(A_log_delta[1]);
    const float s2 = softplus_f(A_log_delta[2]);
    const float c3 = s0 + s1 + s2;
    const float cumh = (h == 0) ? 0.f : (h == 1) ? s0 : (h == 2) ? s0 + s1 : c3;
    const float mg = c3 * (1.0f / 3.0f);
    float alpha = (float)(3 - h) * (1.0f / 3.0f)
                + (cumh - (float)h * mg) * (1.0f / 6.2383246250395075f);
    alpha = fminf(fmaxf(alpha, 0.0f), 1.0f);
    const float expA = expf(base + cumh);
    const int t = row & (Tn - 1);
    const float pf = expf(-alpha * logf((float)(t + 1)));
    float4 a4 = *(const float4*)&qka[(size_t)row * 1536 + 1024 + col];
    float4 db = *(const float4*)&dt_bias[col];
    float4 e;
    e.x = expf(-expA * softplus_f(a4.x + db.x) * pf);
    e.y = expf(-expA * softplus_f(a4.y + db.y) * pf);
    e.z = expf(-expA * softplus_f(a4.z + db.z) * pf);
    e.w = expf(-expA * softplus_f(a4.w + db.w) * pf);
    *(float4*)&Eo[(size_t)row * KDn * 4 / 4 + col] = e; // KDn*? -> row*512
}

// ---------- chunked GLA recurrence ----------
// qka: [8192][1536] fp32 (q 0-511 pre-scaled | k 512-1023 | a 1024-1535). vg: [8192][2048].

__global__ __launch_bounds__(256) void gla_state(const float* __restrict__ qka,
    const float* __restrict__ E, const float* __restrict__ vg, float* __restrict__ Sl)
{
    const int tid = threadIdx.x;
    const int part = tid & 15, dvi = tid >> 4;
    const int dvb = blockIdx.x, bh = blockIdx.y, c = blockIdx.z;
    const int b = bh >> 2, h = bh & 3;
    const int t0 = c * CL;
    const float* kp = qka + (size_t)(b * Tn + t0) * 1536 + 512 + h * DKn + part * 4;
    const float* Ep = E  + (size_t)(b * Tn + t0) * KDn  + h * DKn + part * 4;
    const float* vp = vg + (size_t)(b * Tn + t0) * 2048 + h * DVn + dvb * 64 + dvi * 4;

    float S[8][4];
    #pragma unroll
    for (int i = 0; i < 8; ++i)
        #pragma unroll
        for (int j = 0; j < 4; ++j) S[i][j] = 0.f;

    #pragma unroll 2
    for (int t = 0; t < CL; ++t) {
        float4 kA = *(const float4*)kp;
        float4 kB = *(const float4*)(kp + 64);
        float4 eA = *(const float4*)Ep;
        float4 eB = *(const float4*)(Ep + 64);
        float4 vv = *(const float4*)vp;
        kp += 1536; Ep += KDn; vp += 2048;
        float kr[8] = {kA.x,kA.y,kA.z,kA.w,kB.x,kB.y,kB.z,kB.w};
        float er[8] = {eA.x,eA.y,eA.z,eA.w,eB.x,eB.y,eB.z,eB.w};
        float vr[4] = {vv.x,vv.y,vv.z,vv.w};
        #pragma unroll
        for (int i = 0; i < 8; ++i)
            #pragma unroll
            for (int j = 0; j < 4; ++j)
                S[i][j] = S[i][j] * er[i] + kr[i] * vr[j];
    }
    float* sp = Sl + (((size_t)c * 16 + bh) << 15);
    #pragma unroll
    for (int i = 0; i < 8; ++i) {
        const int dk = (i < 4) ? part * 4 + i : 64 + part * 4 + (i - 4);
        *(float4*)&sp[dk * DVn + dvb * 64 + dvi * 4] = make_float4(S[i][0], S[i][1], S[i][2], S[i][3]);
    }
}

__global__ void decay_prod(const float* __restrict__ E, float* __restrict__ Dc) {
    const int dk = threadIdx.x;           // 0..127
    const int c = blockIdx.x, bh = blockIdx.y;
    const int b = bh >> 2, h = bh & 3;
    const float* Ep = E + (size_t)(b * Tn + c * CL) * KDn + h * DKn + dk;
    float p = 1.f;
    for (int t = 0; t < CL; ++t) { p *= *Ep; Ep += KDn; }
    Dc[(c * 16 + bh) * DKn + dk] = p;
}

// sequential chunk combine (float4 over dv): overwrite Sl[c] with chunk-c START state
__global__ __launch_bounds__(256) void combine(float* __restrict__ Sl,
                                               const float* __restrict__ Dc) {
    const int bh = blockIdx.y;
    const int e4 = blockIdx.x * 256 + threadIdx.x;   // 0..8191 float4 per state
    const int dk = e4 >> 6;
    float4 s = make_float4(0.f, 0.f, 0.f, 0.f);
    for (int c = 0; c < NC; ++c) {
        float4* p = (float4*)(Sl + (((size_t)c * 16 + bh) << 15)) + e4;
        float4 local = *p;
        *p = s;
        const float d = Dc[(c * 16 + bh) * DKn + dk];
        s.x = s.x * d + local.x;  s.y = s.y * d + local.y;
        s.z = s.z * d + local.z;  s.w = s.w * d + local.w;
    }
}

__global__ __launch_bounds__(256) void gla_out(const float* __restrict__ qka,
    const float* __restrict__ E, const float* __restrict__ vg,
    const float* __restrict__ Sl, float* __restrict__ o)
{
    const int tid = threadIdx.x;
    const int part = tid & 15, dvi = tid >> 4;
    const int dvb = blockIdx.x, bh = blockIdx.y, c = blockIdx.z;
    const int b = bh >> 2, h = bh & 3;
    const int t0 = c * CL;
    const float* qp = qka + (size_t)(b * Tn + t0) * 1536 + h * DKn + part * 4;
    const float* Ep = E  + (size_t)(b * Tn + t0) * KDn  + h * DKn + part * 4;
    const float* vp = vg + (size_t)(b * Tn + t0) * 2048 + h * DVn + dvb * 64 + dvi * 4;
    float* op = o + (size_t)(b * Tn + t0) * VDn + h * DVn + dvb * 64 + dvi * 4;

    const float* sp = Sl + (((size_t)c * 16 + bh) << 15);
    float S[8][4];
    #pragma unroll
    for (int i = 0; i < 8; ++i) {
        const int dk = (i < 4) ? part * 4 + i : 64 + part * 4 + (i - 4);
        float4 s4 = *(const float4*)&sp[dk * DVn + dvb * 64 + dvi * 4];
        S[i][0] = s4.x; S[i][1] = s4.y; S[i][2] = s4.z; S[i][3] = s4.w;
    }

    #pragma unroll 2
    for (int t = 0; t < CL; ++t) {
        float4 qA = *(const float4*)qp;
        float4 qB = *(const float4*)(qp + 64);
        float4 kA = *(const float4*)(qp + 512);
        float4 kB = *(const float4*)(qp + 576);
        float4 eA = *(const float4*)Ep;
        float4 eB = *(const float4*)(Ep + 64);
        float4 vv = *(const float4*)vp;
        qp += 1536; Ep += KDn; vp += 2048;
        float qr[8] = {qA.x,qA.y,qA.z,qA.w,qB.x,qB.y,qB.z,qB.w};
        float kr[8] = {kA.x,kA.y,kA.z,kA.w,kB.x,kB.y,kB.z,kB.w};
        float er[8] = {eA.x,eA.y,eA.z,eA.w,eB.x,eB.y,eB.z,eB.w};
        float vr[4] = {vv.x,vv.y,vv.z,vv.w};
        float p[4] = {0.f, 0.f, 0.f, 0.f};
        #pragma unroll
        for (int i = 0; i < 8; ++i) {
            #pragma unroll
            for (int j = 0; j < 4; ++j) {
                S[i][j] = S[i][j] * er[i] + kr[i] * vr[j];
                p[j] += qr[i] * S[i][j];
            }
        }
        #pragma unroll
        for (int j = 0; j < 4; ++j) p[j] = dpp_red16(p[j]);
        if (part == 0) *(float4*)op = make_float4(p[0], p[1], p[2], p[3]);
        op += VDn;
    }
}

// ---------- RMSNorm + swish gate -> bf16 ----------
__global__ __launch_bounds__(256) void rms_gate(const float* __restrict__ o,
    const float* __restrict__ vg, const float* __restrict__ wt,
    ushort* __restrict__ obf)
{
    const int tid = threadIdx.x;
    const int w = tid >> 6, lane = tid & 63;
    const int row = blockIdx.x * 4 + w;     // n*H + h
    const int n = row >> 2, h = row & 3;
    const size_t ob_base = (size_t)n * VDn + h * DVn + lane * 4;
    const size_t g_base  = (size_t)n * 2048 + 1024 + h * DVn + lane * 4;

    float4 o4 = *(const float4*)&o[ob_base];
    float ss = o4.x*o4.x + o4.y*o4.y + o4.z*o4.z + o4.w*o4.w;
    #pragma unroll
    for (int m = 1; m < 64; m <<= 1) ss += __shfl_xor(ss, m);
    const float r = rsqrtf(ss * (1.0f / DVn) + 1e-5f);

    float4 g4 = *(const float4*)&vg[g_base];
    float4 w4 = *(const float4*)&wt[h * DVn + lane * 4];
    ushort4 u;
    u.x = f2bf(o4.x * r * w4.x * (g4.x / (1.0f + expf(-g4.x))));
    u.y = f2bf(o4.y * r * w4.y * (g4.y / (1.0f + expf(-g4.y))));
    u.z = f2bf(o4.z * r * w4.z * (g4.z / (1.0f + expf(-g4.z))));
    u.w = f2bf(o4.w * r * w4.w * (g4.w / (1.0f + expf(-g4.w))));
    *(ushort4*)&obf[ob_base] = u;
}

extern "C" void kernel_launch(void* const* d_in, const int* in_sizes, int n_in,
                              void* d_out, int out_size, void* d_ws, size_t ws_size,
                              hipStream_t stream) {
    const float* hs          = (const float*)d_in[0];
    const float* Wq          = (const float*)d_in[1];
    const float* Wk          = (const float*)d_in[2];
    const float* Wv          = (const float*)d_in[3];
    const float* Wg          = (const float*)d_in[4];
    const float* Wa          = (const float*)d_in[5];
    const float* Wo          = (const float*)d_in[6];
    const float* A_log_base  = (const float*)d_in[7];
    const float* A_log_delta = (const float*)d_in[8];
    const float* dt_bias     = (const float*)d_in[9];
    const float* gnw         = (const float*)d_in[10];
    float* out = (float*)d_out;

    char* ws = (char*)d_ws;
    float*  qka  = (float*)(ws);                           // 48MB [8192][1536] q|k|a
    float*  vgb  = (float*)(ws + ((size_t)48  << 20));     // 64MB [8192][2048] v|g
    float*  Eb   = (float*)(ws + ((size_t)112 << 20));     // 16MB [8192][512]
    float*  ob   = (float*)(ws + ((size_t)128 << 20));     // 32MB [8192][1024]
    ushort* hsb  = (ushort*)(ws + ((size_t)128 << 20));    // 16MB overlay (dead before ob)
    ushort* Wqkab= (ushort*)(ws + ((size_t)144 << 20));    //  3MB overlay
    ushort* Wvgb = (ushort*)(ws + ((size_t)148 << 20));    //  4MB overlay
    float*  Sl   = (float*)(ws + ((size_t)160 << 20));     // 32MB [16][16][128][256]
    float*  Dc   = (float*)(ws + ((size_t)192 << 20));     // 128KB
    ushort* Wob  = (ushort*)(ws + ((size_t)193 << 20));    //  2MB
    ushort* obf  = (ushort*)qka;                           // reuse qka after gla_out

    // casts
    cast_f2b<<<NROWS * Dn / 4 / 256, 256, 0, stream>>>(hs, hsb, NROWS * Dn / 4);
    cast_f2b<<<512,  256, 0, stream>>>(Wq, Wqkab,              KDn * Dn / 4);
    cast_f2b<<<512,  256, 0, stream>>>(Wk, Wqkab + KDn * Dn,   KDn * Dn / 4);
    cast_f2b<<<512,  256, 0, stream>>>(Wa, Wqkab + 2*KDn * Dn, KDn * Dn / 4);
    cast_f2b<<<1024, 256, 0, stream>>>(Wv, Wvgb,               VDn * Dn / 4);
    cast_f2b<<<1024, 256, 0, stream>>>(Wg, Wvgb + VDn * Dn,    VDn * Dn / 4);
    cast_f2b<<<1024, 256, 0, stream>>>(Wo, Wob,                VDn * Dn / 4);

    // projections (q|k|a fused; v|g fused)
    mm_bf16<1><<<dim3(12, 64), 256, 0, stream>>>(hsb, Wqkab, qka, 1536);
    mm_bf16<0><<<dim3(16, 64), 256, 0, stream>>>(hsb, Wvgb, vgb, 2048);
    gate_e<<<NROWS * KDn * 4 / 4 / 256, 256, 0, stream>>>(qka, dt_bias, A_log_base, A_log_delta, Eb);

    // chunked recurrence
    gla_state<<<dim3(4, 16, NC), 256, 0, stream>>>(qka, Eb, vgb, Sl);
    decay_prod<<<dim3(NC, 16), 128, 0, stream>>>(Eb, Dc);
    combine<<<dim3(32, 16), 256, 0, stream>>>(Sl, Dc);
    gla_out<<<dim3(4, 16, NC), 256, 0, stream>>>(qka, Eb, vgb, Sl, ob);

    // epilogue
    rms_gate<<<NROWS * Hn / 4, 256, 0, stream>>>(ob, vgb, gnw, obf);
    mm_bf16<0><<<dim3(8, 64), 256, 0, stream>>>(obf, Wob, out, 1024);
}

// Round 4
// 529.315 us; speedup vs baseline: 3.0482x; 1.0210x over previous
//
#include <hip/hip_runtime.h>
#include <math.h>

#define Bn   4
#define Tn   2048
#define Dn   1024
#define Hn   4
#define DKn  128
#define DVn  256
#define KDn  512
#define VDn  1024
#define NROWS 8192
#define NC   32
#define CL   64
#define LOG_T_REF_F 6.2383246250395075f

using bf16x8 = __attribute__((ext_vector_type(8))) short;
using f32x4  = __attribute__((ext_vector_type(4))) float;

__device__ __forceinline__ float softplus_f(float x) {
    return fmaxf(x, 0.0f) + log1pf(expf(-fabsf(x)));
}
__device__ __forceinline__ ushort f2bf(float f) {
    unsigned u = __float_as_uint(f);
    u = (u + 0x7fffu + ((u >> 16) & 1u)) >> 16;
    return (ushort)u;
}
__device__ __forceinline__ void gload16(const void* g, void* l) {
    __builtin_amdgcn_global_load_lds(
        (const __attribute__((address_space(1))) unsigned*)g,
        (__attribute__((address_space(3))) unsigned*)l, 16, 0, 0);
}
// full-sum butterfly over each aligned 16-lane group, pure VALU (DPP)
__device__ __forceinline__ float dpp_red16(float p) {
    p += __int_as_float(__builtin_amdgcn_mov_dpp(__float_as_int(p), 0xB1,  0xF, 0xF, true)); // xor1
    p += __int_as_float(__builtin_amdgcn_mov_dpp(__float_as_int(p), 0x4E,  0xF, 0xF, true)); // xor2
    p += __int_as_float(__builtin_amdgcn_mov_dpp(__float_as_int(p), 0x124, 0xF, 0xF, true)); // ror4
    p += __int_as_float(__builtin_amdgcn_mov_dpp(__float_as_int(p), 0x128, 0xF, 0xF, true)); // ror8
    return p;
}

// ---------- cast fp32 -> bf16 ----------
__global__ __launch_bounds__(256) void cast_f2b(const float* __restrict__ x,
                                                ushort* __restrict__ y, int n4) {
    int i = blockIdx.x * 256 + threadIdx.x;
    if (i < n4) {
        float4 v = *(const float4*)&x[i * 4];
        ushort4 o;
        o.x = f2bf(v.x); o.y = f2bf(v.y); o.z = f2bf(v.z); o.w = f2bf(v.w);
        *(ushort4*)&y[i * 4] = o;
    }
}

// ---------- bf16 MFMA GEMM, global_load_lds staging (m97 structure) ----------
// A[M x 1024] @ Bw[Ncols x 1024]^T, fp32 accumulate.
// MODE 0: plain fp32 -> C [.][1024]
// MODE 1 (qka GEMM, Ncols=1536): cols<512 scaled fp32 -> C (qk [.][1024]);
//         cols 512..1023 fp32 -> C; cols>=1024: gate transform -> Eo [.][512]
// MODE 2 (vg GEMM, Ncols=2048): cols<1024 fp32 -> C (v [.][1024]);
//         cols>=1024 -> bf16 C2 (g [.][1024])
template<int MODE>
__global__ __launch_bounds__(256) void mm2(const ushort* __restrict__ A,
    const ushort* __restrict__ Bw, float* __restrict__ C,
    ushort* __restrict__ C2, float* __restrict__ Eo,
    const float* __restrict__ dt_bias, const float* __restrict__ A_log_base,
    const float* __restrict__ A_log_delta)
{
    __shared__ __align__(16) ushort As[4][128][8];   // [kslot(8 bf16)][row][8]
    __shared__ __align__(16) ushort Bs[4][128][8];
    const int tid = threadIdx.x;
    const int lane = tid & 63, w = tid >> 6;
    const int l15 = lane & 15, lg = lane >> 4;
    const int wr = (w >> 1) << 6, wc = (w & 1) << 6;
    const int row0 = blockIdx.y << 7, col0 = blockIdx.x << 7;

    const ushort* Ag0 = A  + (size_t)(row0 + lane) * Dn + w * 8;
    const ushort* Ag1 = A  + (size_t)(row0 + 64 + lane) * Dn + w * 8;
    const ushort* Bg0 = Bw + (size_t)(col0 + lane) * Dn + w * 8;
    const ushort* Bg1 = Bw + (size_t)(col0 + 64 + lane) * Dn + w * 8;
    ushort* lA0 = &As[w][0][0];
    ushort* lA1 = &As[w][64][0];
    ushort* lB0 = &Bs[w][0][0];
    ushort* lB1 = &Bs[w][64][0];

    f32x4 acc[4][4];
    #pragma unroll
    for (int m = 0; m < 4; ++m)
        #pragma unroll
        for (int n = 0; n < 4; ++n)
            acc[m][n] = (f32x4){0.f, 0.f, 0.f, 0.f};

    for (int kt = 0; kt < Dn; kt += 32) {
        __syncthreads();
        gload16(Ag0 + kt, lA0);
        gload16(Ag1 + kt, lA1);
        gload16(Bg0 + kt, lB0);
        gload16(Bg1 + kt, lB1);
        __syncthreads();
        bf16x8 af[4], bv[4];
        #pragma unroll
        for (int m = 0; m < 4; ++m) af[m] = *(const bf16x8*)&As[lg][wr + m*16 + l15][0];
        #pragma unroll
        for (int n = 0; n < 4; ++n) bv[n] = *(const bf16x8*)&Bs[lg][wc + n*16 + l15][0];
        #pragma unroll
        for (int m = 0; m < 4; ++m)
            #pragma unroll
            for (int n = 0; n < 4; ++n)
                acc[m][n] = __builtin_amdgcn_mfma_f32_16x16x32_bf16(af[m], bv[n], acc[m][n], 0, 0, 0);
    }

    if (MODE == 1 && col0 >= 1024) {
        // gate-transform epilogue: E = exp(-exp(A_log[h]) * softplus(a+dt_bias) * pos^-alpha)
        const float base_ = A_log_base[0];
        const float s0 = softplus_f(A_log_delta[0]);
        const float s1 = softplus_f(A_log_delta[1]);
        const float s2 = softplus_f(A_log_delta[2]);
        const float c3 = s0 + s1 + s2;
        const float mg = c3 * (1.0f / 3.0f);
        float pf[4][4];
        #pragma unroll
        for (int m = 0; m < 4; ++m) {
            const int row = row0 + wr + m * 16 + lg * 4;
            #pragma unroll
            for (int r = 0; r < 4; ++r) {
                const int t = (row + r) & (Tn - 1);
                pf[m][r] = logf((float)(t + 1));
            }
        }
        #pragma unroll
        for (int n = 0; n < 4; ++n) {
            const int dk = col0 - 1024 + wc + n * 16 + l15;   // 0..511
            const int h = dk >> 7;
            const float cumh = (h == 0) ? 0.f : (h == 1) ? s0 : (h == 2) ? s0 + s1 : c3;
            float alpha = (float)(3 - h) * (1.0f / 3.0f)
                        + (cumh - (float)h * mg) * (1.0f / LOG_T_REF_F);
            alpha = fminf(fmaxf(alpha, 0.0f), 1.0f);
            const float expA = expf(base_ + cumh);
            const float db = dt_bias[dk];
            #pragma unroll
            for (int m = 0; m < 4; ++m) {
                const int row = row0 + wr + m * 16 + lg * 4;
                #pragma unroll
                for (int r = 0; r < 4; ++r) {
                    const float p = expf(-alpha * pf[m][r]);
                    Eo[(size_t)(row + r) * KDn + dk] =
                        expf(-expA * softplus_f(acc[m][n][r] + db) * p);
                }
            }
        }
    } else if (MODE == 2 && col0 >= 1024) {
        // bf16 g output
        #pragma unroll
        for (int m = 0; m < 4; ++m) {
            const int row = row0 + wr + m * 16 + lg * 4;
            #pragma unroll
            for (int n = 0; n < 4; ++n) {
                const int col = col0 - 1024 + wc + n * 16 + l15;
                #pragma unroll
                for (int r = 0; r < 4; ++r)
                    C2[(size_t)(row + r) * 1024 + col] = f2bf(acc[m][n][r]);
            }
        }
    } else {
        const float s = (MODE == 1 && col0 < 512) ? 0.08838834764831845f : 1.0f;
        #pragma unroll
        for (int m = 0; m < 4; ++m) {
            const int row = row0 + wr + m * 16 + lg * 4;
            #pragma unroll
            for (int n = 0; n < 4; ++n) {
                const int col = col0 + wc + n * 16 + l15;
                #pragma unroll
                for (int r = 0; r < 4; ++r)
                    C[(size_t)(row + r) * 1024 + col] = acc[m][n][r] * s;
            }
        }
    }
}

// ---------- chunked GLA recurrence ----------
// qk: [8192][1024] fp32 (q 0-511 pre-scaled | k 512-1023). vb: [8192][1024] fp32.
// E: [8192][512] fp32.  Thread (part=tid&15, dvi=tid>>4) owns
// dk {part*4..+4, 64+part*4..+4} x dv {dvb*64+dvi*4..+4}.

__global__ __launch_bounds__(256) void gla_state(const float* __restrict__ qk,
    const float* __restrict__ E, const float* __restrict__ vb, float* __restrict__ Sl)
{
    const int tid = threadIdx.x;
    const int part = tid & 15, dvi = tid >> 4;
    const int dvb = blockIdx.x, bh = blockIdx.y, c = blockIdx.z;
    const int b = bh >> 2, h = bh & 3;
    const int t0 = c * CL;
    const float* kp = qk + (size_t)(b * Tn + t0) * 1024 + 512 + h * DKn + part * 4;
    const float* Ep = E  + (size_t)(b * Tn + t0) * KDn  + h * DKn + part * 4;
    const float* vp = vb + (size_t)(b * Tn + t0) * 1024 + h * DVn + dvb * 64 + dvi * 4;

    float S[8][4];
    #pragma unroll
    for (int i = 0; i < 8; ++i)
        #pragma unroll
        for (int j = 0; j < 4; ++j) S[i][j] = 0.f;

    #pragma unroll 2
    for (int t = 0; t < CL; ++t) {
        float4 kA = *(const float4*)kp;
        float4 kB = *(const float4*)(kp + 64);
        float4 eA = *(const float4*)Ep;
        float4 eB = *(const float4*)(Ep + 64);
        float4 vv = *(const float4*)vp;
        kp += 1024; Ep += KDn; vp += 1024;
        float kr[8] = {kA.x,kA.y,kA.z,kA.w,kB.x,kB.y,kB.z,kB.w};
        float er[8] = {eA.x,eA.y,eA.z,eA.w,eB.x,eB.y,eB.z,eB.w};
        float vr[4] = {vv.x,vv.y,vv.z,vv.w};
        #pragma unroll
        for (int i = 0; i < 8; ++i)
            #pragma unroll
            for (int j = 0; j < 4; ++j)
                S[i][j] = S[i][j] * er[i] + kr[i] * vr[j];
    }
    float* sp = Sl + (((size_t)c * 16 + bh) << 15);
    #pragma unroll
    for (int i = 0; i < 8; ++i) {
        const int dk = (i < 4) ? part * 4 + i : 64 + part * 4 + (i - 4);
        *(float4*)&sp[dk * DVn + dvb * 64 + dvi * 4] = make_float4(S[i][0], S[i][1], S[i][2], S[i][3]);
    }
}

__global__ void decay_prod(const float* __restrict__ E, float* __restrict__ Dc) {
    const int dk = threadIdx.x;           // 0..127
    const int c = blockIdx.x, bh = blockIdx.y;
    const int b = bh >> 2, h = bh & 3;
    const float* Ep = E + (size_t)(b * Tn + c * CL) * KDn + h * DKn + dk;
    float p = 1.f;
    for (int t = 0; t < CL; ++t) { p *= *Ep; Ep += KDn; }
    Dc[(c * 16 + bh) * DKn + dk] = p;
}

// sequential chunk combine (float4 over dv): overwrite Sl[c] with chunk-c START state
__global__ __launch_bounds__(256) void combine(float* __restrict__ Sl,
                                               const float* __restrict__ Dc) {
    const int bh = blockIdx.y;
    const int e4 = blockIdx.x * 256 + threadIdx.x;   // 0..8191 float4 per state
    const int dk = e4 >> 6;
    float4 s = make_float4(0.f, 0.f, 0.f, 0.f);
    for (int c = 0; c < NC; ++c) {
        float4* p = (float4*)(Sl + (((size_t)c * 16 + bh) << 15)) + e4;
        float4 local = *p;
        *p = s;
        const float d = Dc[(c * 16 + bh) * DKn + dk];
        s.x = s.x * d + local.x;  s.y = s.y * d + local.y;
        s.z = s.z * d + local.z;  s.w = s.w * d + local.w;
    }
}

__global__ __launch_bounds__(256) void gla_out(const float* __restrict__ qk,
    const float* __restrict__ E, const float* __restrict__ vb,
    const float* __restrict__ Sl, float* __restrict__ o)
{
    const int tid = threadIdx.x;
    const int part = tid & 15, dvi = tid >> 4;
    const int dvb = blockIdx.x, bh = blockIdx.y, c = blockIdx.z;
    const int b = bh >> 2, h = bh & 3;
    const int t0 = c * CL;
    const float* qp = qk + (size_t)(b * Tn + t0) * 1024 + h * DKn + part * 4;
    const float* Ep = E  + (size_t)(b * Tn + t0) * KDn  + h * DKn + part * 4;
    const float* vp = vb + (size_t)(b * Tn + t0) * 1024 + h * DVn + dvb * 64 + dvi * 4;
    float* op = o + (size_t)(b * Tn + t0) * VDn + h * DVn + dvb * 64 + dvi * 4;

    const float* sp = Sl + (((size_t)c * 16 + bh) << 15);
    float S[8][4];
    #pragma unroll
    for (int i = 0; i < 8; ++i) {
        const int dk = (i < 4) ? part * 4 + i : 64 + part * 4 + (i - 4);
        float4 s4 = *(const float4*)&sp[dk * DVn + dvb * 64 + dvi * 4];
        S[i][0] = s4.x; S[i][1] = s4.y; S[i][2] = s4.z; S[i][3] = s4.w;
    }

    #pragma unroll 2
    for (int t = 0; t < CL; ++t) {
        float4 qA = *(const float4*)qp;
        float4 qB = *(const float4*)(qp + 64);
        float4 kA = *(const float4*)(qp + 512);
        float4 kB = *(const float4*)(qp + 576);
        float4 eA = *(const float4*)Ep;
        float4 eB = *(const float4*)(Ep + 64);
        float4 vv = *(const float4*)vp;
        qp += 1024; Ep += KDn; vp += 1024;
        float qr[8] = {qA.x,qA.y,qA.z,qA.w,qB.x,qB.y,qB.z,qB.w};
        float kr[8] = {kA.x,kA.y,kA.z,kA.w,kB.x,kB.y,kB.z,kB.w};
        float er[8] = {eA.x,eA.y,eA.z,eA.w,eB.x,eB.y,eB.z,eB.w};
        float vr[4] = {vv.x,vv.y,vv.z,vv.w};
        float p[4] = {0.f, 0.f, 0.f, 0.f};
        #pragma unroll
        for (int i = 0; i < 8; ++i) {
            #pragma unroll
            for (int j = 0; j < 4; ++j) {
                S[i][j] = S[i][j] * er[i] + kr[i] * vr[j];
                p[j] += qr[i] * S[i][j];
            }
        }
        #pragma unroll
        for (int j = 0; j < 4; ++j) p[j] = dpp_red16(p[j]);
        if (part == 0) *(float4*)op = make_float4(p[0], p[1], p[2], p[3]);
        op += VDn;
    }
}

// ---------- RMSNorm + swish gate (g in bf16) -> bf16 ----------
__global__ __launch_bounds__(256) void rms_gate(const float* __restrict__ o,
    const ushort* __restrict__ gbf, const float* __restrict__ wt,
    ushort* __restrict__ obf)
{
    const int tid = threadIdx.x;
    const int w = tid >> 6, lane = tid & 63;
    const int row = blockIdx.x * 4 + w;     // n*H + h
    const int n = row >> 2, h = row & 3;
    const size_t ob_base = (size_t)n * VDn + h * DVn + lane * 4;

    float4 o4 = *(const float4*)&o[ob_base];
    float ss = o4.x*o4.x + o4.y*o4.y + o4.z*o4.z + o4.w*o4.w;
    #pragma unroll
    for (int m = 1; m < 64; m <<= 1) ss += __shfl_xor(ss, m);
    const float r = rsqrtf(ss * (1.0f / DVn) + 1e-5f);

    ushort4 gu = *(const ushort4*)&gbf[ob_base];
    float gx = __uint_as_float((unsigned)gu.x << 16);
    float gy = __uint_as_float((unsigned)gu.y << 16);
    float gz = __uint_as_float((unsigned)gu.z << 16);
    float gw = __uint_as_float((unsigned)gu.w << 16);
    float4 w4 = *(const float4*)&wt[h * DVn + lane * 4];
    ushort4 u;
    u.x = f2bf(o4.x * r * w4.x * (gx / (1.0f + expf(-gx))));
    u.y = f2bf(o4.y * r * w4.y * (gy / (1.0f + expf(-gy))));
    u.z = f2bf(o4.z * r * w4.z * (gz / (1.0f + expf(-gz))));
    u.w = f2bf(o4.w * r * w4.w * (gw / (1.0f + expf(-gw))));
    *(ushort4*)&obf[ob_base] = u;
}

extern "C" void kernel_launch(void* const* d_in, const int* in_sizes, int n_in,
                              void* d_out, int out_size, void* d_ws, size_t ws_size,
                              hipStream_t stream) {
    const float* hs          = (const float*)d_in[0];
    const float* Wq          = (const float*)d_in[1];
    const float* Wk          = (const float*)d_in[2];
    const float* Wv          = (const float*)d_in[3];
    const float* Wg          = (const float*)d_in[4];
    const float* Wa          = (const float*)d_in[5];
    const float* Wo          = (const float*)d_in[6];
    const float* A_log_base  = (const float*)d_in[7];
    const float* A_log_delta = (const float*)d_in[8];
    const float* dt_bias     = (const float*)d_in[9];
    const float* gnw         = (const float*)d_in[10];
    float* out = (float*)d_out;

    char* ws = (char*)d_ws;
    float*  qk   = (float*)(ws);                           // 32MB [8192][1024] q|k
    float*  vb   = (float*)(ws + ((size_t)32  << 20));     // 32MB [8192][1024] v fp32
    float*  Eb   = (float*)(ws + ((size_t)64  << 20));     // 16MB [8192][512]
    float*  Sl   = (float*)(ws + ((size_t)80  << 20));     // 64MB [32][16][128][256]
    float*  ob   = (float*)(ws + ((size_t)144 << 20));     // 32MB [8192][1024]
    ushort* hsb  = (ushort*)(ws + ((size_t)144 << 20));    // 16MB overlay on ob (dead before gla_out)
    ushort* gbf  = (ushort*)(ws + ((size_t)176 << 20));    // 16MB [8192][1024] g bf16
    ushort* Wqkab= (ushort*)(ws + ((size_t)192 << 20));    //  3MB [1536][1024] bf16
    ushort* Wvgb = (ushort*)(ws + ((size_t)195 << 20));    //  4MB [2048][1024] bf16
    ushort* Wob  = (ushort*)(ws + ((size_t)199 << 20));    //  2MB [1024][1024] bf16
    float*  Dc   = (float*)(ws + ((size_t)201 << 20));     // 256KB [32][16][128]
    ushort* obf  = (ushort*)qk;                            // reuse qk after gla_out

    // casts
    cast_f2b<<<NROWS * Dn / 4 / 256, 256, 0, stream>>>(hs, hsb, NROWS * Dn / 4);
    cast_f2b<<<512,  256, 0, stream>>>(Wq, Wqkab,              KDn * Dn / 4);
    cast_f2b<<<512,  256, 0, stream>>>(Wk, Wqkab + KDn * Dn,   KDn * Dn / 4);
    cast_f2b<<<512,  256, 0, stream>>>(Wa, Wqkab + 2*KDn * Dn, KDn * Dn / 4);
    cast_f2b<<<1024, 256, 0, stream>>>(Wv, Wvgb,               VDn * Dn / 4);
    cast_f2b<<<1024, 256, 0, stream>>>(Wg, Wvgb + VDn * Dn,    VDn * Dn / 4);
    cast_f2b<<<1024, 256, 0, stream>>>(Wo, Wob,                VDn * Dn / 4);

    // projections: q|k (scaled q) + fused gate transform -> Eb ; v fp32 + g bf16
    mm2<1><<<dim3(12, 64), 256, 0, stream>>>(hsb, Wqkab, qk, nullptr, Eb,
                                             dt_bias, A_log_base, A_log_delta);
    mm2<2><<<dim3(16, 64), 256, 0, stream>>>(hsb, Wvgb, vb, gbf, nullptr,
                                             nullptr, nullptr, nullptr);

    // chunked recurrence (NC=32 chunks of 64 -> full occupancy)
    gla_state<<<dim3(4, 16, NC), 256, 0, stream>>>(qk, Eb, vb, Sl);
    decay_prod<<<dim3(NC, 16), 128, 0, stream>>>(Eb, Dc);
    combine<<<dim3(32, 16), 256, 0, stream>>>(Sl, Dc);
    gla_out<<<dim3(4, 16, NC), 256, 0, stream>>>(qk, Eb, vb, Sl, ob);

    // epilogue
    rms_gate<<<NROWS * Hn / 4, 256, 0, stream>>>(ob, gbf, gnw, obf);
    mm2<0><<<dim3(8, 64), 256, 0, stream>>>(obf, Wob, out, nullptr, nullptr,
                                            nullptr, nullptr, nullptr);
}

// Round 5
// 511.026 us; speedup vs baseline: 3.1572x; 1.0358x over previous
//
#include <hip/hip_runtime.h>
#include <math.h>

#define Bn   4
#define Tn   2048
#define Dn   1024
#define Hn   4
#define DKn  128
#define DVn  256
#define KDn  512
#define VDn  1024
#define NROWS 8192
#define NC   32
#define CLS  64
#define NCO  16
#define CLO  128
#define LOG_T_REF_F 6.2383246250395075f

using bf16x8 = __attribute__((ext_vector_type(8))) short;
using f32x4  = __attribute__((ext_vector_type(4))) float;
using f32x2  = __attribute__((ext_vector_type(2))) float;

__device__ __forceinline__ float softplus_f(float x) {
    return fmaxf(x, 0.0f) + log1pf(expf(-fabsf(x)));
}
__device__ __forceinline__ ushort f2bf(float f) {
    unsigned u = __float_as_uint(f);
    u = (u + 0x7fffu + ((u >> 16) & 1u)) >> 16;
    return (ushort)u;
}
__device__ __forceinline__ void gload16(const void* g, void* l) {
    __builtin_amdgcn_global_load_lds(
        (const __attribute__((address_space(1))) unsigned*)g,
        (__attribute__((address_space(3))) unsigned*)l, 16, 0, 0);
}
// full-sum butterfly over each aligned 16-lane group, pure VALU (DPP)
__device__ __forceinline__ float dpp_red16(float p) {
    p += __int_as_float(__builtin_amdgcn_mov_dpp(__float_as_int(p), 0xB1,  0xF, 0xF, true)); // xor1
    p += __int_as_float(__builtin_amdgcn_mov_dpp(__float_as_int(p), 0x4E,  0xF, 0xF, true)); // xor2
    p += __int_as_float(__builtin_amdgcn_mov_dpp(__float_as_int(p), 0x124, 0xF, 0xF, true)); // ror4
    p += __int_as_float(__builtin_amdgcn_mov_dpp(__float_as_int(p), 0x128, 0xF, 0xF, true)); // ror8
    return p;
}

// ---------- cast fp32 -> bf16 ----------
__global__ __launch_bounds__(256) void cast_f2b(const float* __restrict__ x,
                                                ushort* __restrict__ y, int n4) {
    int i = blockIdx.x * 256 + threadIdx.x;
    if (i < n4) {
        float4 v = *(const float4*)&x[i * 4];
        ushort4 o;
        o.x = f2bf(v.x); o.y = f2bf(v.y); o.z = f2bf(v.z); o.w = f2bf(v.w);
        *(ushort4*)&y[i * 4] = o;
    }
}

// ---------- bf16 MFMA GEMM, global_load_lds staging, XCD-swizzled 1-D grid ----------
// A[M x 1024] @ Bw[NX*128 x 1024]^T, fp32 accumulate. Grid = NX*64 blocks (multiple of 8).
// MODE 0: plain fp32 -> C [.][1024]
// MODE 1 (qka, NX=12): cols<512 scaled fp32 -> C; 512..1023 fp32 -> C; >=1024 gate -> Eo [.][512]
// MODE 2 (vg,  NX=16): cols<1024 fp32 -> C (v); >=1024 -> bf16 C2 (g)
template<int MODE, int NX>
__global__ __launch_bounds__(256) void mm2(const ushort* __restrict__ A,
    const ushort* __restrict__ Bw, float* __restrict__ C,
    ushort* __restrict__ C2, float* __restrict__ Eo,
    const float* __restrict__ dt_bias, const float* __restrict__ A_log_base,
    const float* __restrict__ A_log_delta)
{
    __shared__ __align__(16) ushort As[4][128][8];   // [kslot(8 bf16)][row][8]
    __shared__ __align__(16) ushort Bs[4][128][8];
    const int raw = blockIdx.x;
    const int nwg = NX * 64;
    const int l = (raw & 7) * (nwg >> 3) + (raw >> 3);   // XCD-chunked remap
    const int bx = l % NX, by = l / NX;
    const int tid = threadIdx.x;
    const int lane = tid & 63, w = tid >> 6;
    const int l15 = lane & 15, lg = lane >> 4;
    const int wr = (w >> 1) << 6, wc = (w & 1) << 6;
    const int row0 = by << 7, col0 = bx << 7;

    const ushort* Ag0 = A  + (size_t)(row0 + lane) * Dn + w * 8;
    const ushort* Ag1 = A  + (size_t)(row0 + 64 + lane) * Dn + w * 8;
    const ushort* Bg0 = Bw + (size_t)(col0 + lane) * Dn + w * 8;
    const ushort* Bg1 = Bw + (size_t)(col0 + 64 + lane) * Dn + w * 8;
    ushort* lA0 = &As[w][0][0];
    ushort* lA1 = &As[w][64][0];
    ushort* lB0 = &Bs[w][0][0];
    ushort* lB1 = &Bs[w][64][0];

    f32x4 acc[4][4];
    #pragma unroll
    for (int m = 0; m < 4; ++m)
        #pragma unroll
        for (int n = 0; n < 4; ++n)
            acc[m][n] = (f32x4){0.f, 0.f, 0.f, 0.f};

    for (int kt = 0; kt < Dn; kt += 32) {
        __syncthreads();
        gload16(Ag0 + kt, lA0);
        gload16(Ag1 + kt, lA1);
        gload16(Bg0 + kt, lB0);
        gload16(Bg1 + kt, lB1);
        __syncthreads();
        bf16x8 af[4], bv[4];
        #pragma unroll
        for (int m = 0; m < 4; ++m) af[m] = *(const bf16x8*)&As[lg][wr + m*16 + l15][0];
        #pragma unroll
        for (int n = 0; n < 4; ++n) bv[n] = *(const bf16x8*)&Bs[lg][wc + n*16 + l15][0];
        #pragma unroll
        for (int m = 0; m < 4; ++m)
            #pragma unroll
            for (int n = 0; n < 4; ++n)
                acc[m][n] = __builtin_amdgcn_mfma_f32_16x16x32_bf16(af[m], bv[n], acc[m][n], 0, 0, 0);
    }

    if (MODE == 1 && col0 >= 1024) {
        const float base_ = A_log_base[0];
        const float s0 = softplus_f(A_log_delta[0]);
        const float s1 = softplus_f(A_log_delta[1]);
        const float s2 = softplus_f(A_log_delta[2]);
        const float c3 = s0 + s1 + s2;
        const float mg = c3 * (1.0f / 3.0f);
        float pf[4][4];
        #pragma unroll
        for (int m = 0; m < 4; ++m) {
            const int row = row0 + wr + m * 16 + lg * 4;
            #pragma unroll
            for (int r = 0; r < 4; ++r) {
                const int t = (row + r) & (Tn - 1);
                pf[m][r] = logf((float)(t + 1));
            }
        }
        #pragma unroll
        for (int n = 0; n < 4; ++n) {
            const int dk = col0 - 1024 + wc + n * 16 + l15;   // 0..511
            const int h = dk >> 7;
            const float cumh = (h == 0) ? 0.f : (h == 1) ? s0 : (h == 2) ? s0 + s1 : c3;
            float alpha = (float)(3 - h) * (1.0f / 3.0f)
                        + (cumh - (float)h * mg) * (1.0f / LOG_T_REF_F);
            alpha = fminf(fmaxf(alpha, 0.0f), 1.0f);
            const float expA = expf(base_ + cumh);
            const float db = dt_bias[dk];
            #pragma unroll
            for (int m = 0; m < 4; ++m) {
                const int row = row0 + wr + m * 16 + lg * 4;
                #pragma unroll
                for (int r = 0; r < 4; ++r) {
                    const float p = expf(-alpha * pf[m][r]);
                    Eo[(size_t)(row + r) * KDn + dk] =
                        expf(-expA * softplus_f(acc[m][n][r] + db) * p);
                }
            }
        }
    } else if (MODE == 2 && col0 >= 1024) {
        #pragma unroll
        for (int m = 0; m < 4; ++m) {
            const int row = row0 + wr + m * 16 + lg * 4;
            #pragma unroll
            for (int n = 0; n < 4; ++n) {
                const int col = col0 - 1024 + wc + n * 16 + l15;
                #pragma unroll
                for (int r = 0; r < 4; ++r)
                    C2[(size_t)(row + r) * 1024 + col] = f2bf(acc[m][n][r]);
            }
        }
    } else {
        const float s = (MODE == 1 && col0 < 512) ? 0.08838834764831845f : 1.0f;
        #pragma unroll
        for (int m = 0; m < 4; ++m) {
            const int row = row0 + wr + m * 16 + lg * 4;
            #pragma unroll
            for (int n = 0; n < 4; ++n) {
                const int col = col0 + wc + n * 16 + l15;
                #pragma unroll
                for (int r = 0; r < 4; ++r)
                    C[(size_t)(row + r) * 1024 + col] = acc[m][n][r] * s;
            }
        }
    }
}

// ---------- chunked GLA recurrence ----------
// qk: [8192][1024] fp32 (q 0-511 pre-scaled | k 512-1023). vb: [8192][1024] fp32.
// E: [8192][512] fp32. Thread (part=tid&15, dvi=tid>>4) owns
// dk {part*4..+4, 64+part*4..+4} x dv {dvb*64+dvi*4..+4}. Packed f32x2 over dv.

// local states at fine chunks (NC=32 x 64), XCD-swizzled 1-D grid of 2048
__global__ __launch_bounds__(256) void gla_state(const float* __restrict__ qk,
    const float* __restrict__ E, const float* __restrict__ vb, float* __restrict__ Sl)
{
    const int raw = blockIdx.x;
    const int l = (raw & 7) * 256 + (raw >> 3);
    const int dvb = l & 3, bh = (l >> 2) & 15, c = l >> 6;   // c: 0..31
    const int tid = threadIdx.x;
    const int part = tid & 15, dvi = tid >> 4;
    const int b = bh >> 2, h = bh & 3;
    const int t0 = c * CLS;
    const float* kp = qk + (size_t)(b * Tn + t0) * 1024 + 512 + h * DKn + part * 4;
    const float* Ep = E  + (size_t)(b * Tn + t0) * KDn  + h * DKn + part * 4;
    const float* vp = vb + (size_t)(b * Tn + t0) * 1024 + h * DVn + dvb * 64 + dvi * 4;

    f32x2 S01[8], S23[8];
    #pragma unroll
    for (int i = 0; i < 8; ++i) { S01[i] = (f32x2){0.f,0.f}; S23[i] = (f32x2){0.f,0.f}; }

    #pragma unroll 2
    for (int t = 0; t < CLS; ++t) {
        float4 kA = *(const float4*)kp;
        float4 kB = *(const float4*)(kp + 64);
        float4 eA = *(const float4*)Ep;
        float4 eB = *(const float4*)(Ep + 64);
        float4 vv = *(const float4*)vp;
        kp += 1024; Ep += KDn; vp += 1024;
        const f32x2 v01 = (f32x2){vv.x, vv.y};
        const f32x2 v23 = (f32x2){vv.z, vv.w};
        float kr[8] = {kA.x,kA.y,kA.z,kA.w,kB.x,kB.y,kB.z,kB.w};
        float er[8] = {eA.x,eA.y,eA.z,eA.w,eB.x,eB.y,eB.z,eB.w};
        #pragma unroll
        for (int i = 0; i < 8; ++i) {
            const f32x2 kk = (f32x2){kr[i], kr[i]};
            const f32x2 ee = (f32x2){er[i], er[i]};
            S01[i] = S01[i] * ee + kk * v01;
            S23[i] = S23[i] * ee + kk * v23;
        }
    }
    float* sp = Sl + (((size_t)c * 16 + bh) << 15);
    #pragma unroll
    for (int i = 0; i < 8; ++i) {
        const int dk = (i < 4) ? part * 4 + i : 64 + part * 4 + (i - 4);
        *(float4*)&sp[dk * DVn + dvb * 64 + dvi * 4] =
            make_float4(S01[i].x, S01[i].y, S23[i].x, S23[i].y);
    }
}

__global__ void decay_prod(const float* __restrict__ E, float* __restrict__ Dc) {
    const int dk = threadIdx.x;           // 0..127
    const int c = blockIdx.x, bh = blockIdx.y;
    const int b = bh >> 2, h = bh & 3;
    const float* Ep = E + (size_t)(b * Tn + c * CLS) * KDn + h * DKn + dk;
    float p = 1.f;
    for (int t = 0; t < CLS; ++t) { p *= *Ep; Ep += KDn; }
    Dc[(c * 16 + bh) * DKn + dk] = p;
}

// sequential chunk combine: overwrite Sl[c] with chunk-c START state
__global__ __launch_bounds__(256) void combine(float* __restrict__ Sl,
                                               const float* __restrict__ Dc) {
    const int bh = blockIdx.y;
    const int e4 = blockIdx.x * 256 + threadIdx.x;   // 0..8191 float4 per state
    const int dk = e4 >> 6;
    float4 s = make_float4(0.f, 0.f, 0.f, 0.f);
    #pragma unroll 4
    for (int c = 0; c < NC; ++c) {
        float4* p = (float4*)(Sl + (((size_t)c * 16 + bh) << 15)) + e4;
        float4 local = *p;
        const float d = Dc[(c * 16 + bh) * DKn + dk];
        *p = s;
        s.x = s.x * d + local.x;  s.y = s.y * d + local.y;
        s.z = s.z * d + local.z;  s.w = s.w * d + local.w;
    }
}

// output pass at coarse chunks (NCO=16 x 128), start state = Sl[2*co], grid 1024
__global__ __launch_bounds__(256) void gla_out(const float* __restrict__ qk,
    const float* __restrict__ E, const float* __restrict__ vb,
    const float* __restrict__ Sl, float* __restrict__ o)
{
    const int raw = blockIdx.x;
    const int l = (raw & 7) * 128 + (raw >> 3);
    const int dvb = l & 3, bh = (l >> 2) & 15, co = l >> 6;  // co: 0..15
    const int tid = threadIdx.x;
    const int part = tid & 15, dvi = tid >> 4;
    const int b = bh >> 2, h = bh & 3;
    const int t0 = co * CLO;
    const float* qp = qk + (size_t)(b * Tn + t0) * 1024 + h * DKn + part * 4;
    const float* Ep = E  + (size_t)(b * Tn + t0) * KDn  + h * DKn + part * 4;
    const float* vp = vb + (size_t)(b * Tn + t0) * 1024 + h * DVn + dvb * 64 + dvi * 4;
    float* op = o + (size_t)(b * Tn + t0) * VDn + h * DVn + dvb * 64 + dvi * 4;

    const float* sp = Sl + (((size_t)(2 * co) * 16 + bh) << 15);
    f32x2 S01[8], S23[8];
    #pragma unroll
    for (int i = 0; i < 8; ++i) {
        const int dk = (i < 4) ? part * 4 + i : 64 + part * 4 + (i - 4);
        float4 s4 = *(const float4*)&sp[dk * DVn + dvb * 64 + dvi * 4];
        S01[i] = (f32x2){s4.x, s4.y};
        S23[i] = (f32x2){s4.z, s4.w};
    }

    #pragma unroll 2
    for (int t = 0; t < CLO; ++t) {
        float4 qA = *(const float4*)qp;
        float4 qB = *(const float4*)(qp + 64);
        float4 kA = *(const float4*)(qp + 512);
        float4 kB = *(const float4*)(qp + 576);
        float4 eA = *(const float4*)Ep;
        float4 eB = *(const float4*)(Ep + 64);
        float4 vv = *(const float4*)vp;
        qp += 1024; Ep += KDn; vp += 1024;
        const f32x2 v01 = (f32x2){vv.x, vv.y};
        const f32x2 v23 = (f32x2){vv.z, vv.w};
        float qr[8] = {qA.x,qA.y,qA.z,qA.w,qB.x,qB.y,qB.z,qB.w};
        float kr[8] = {kA.x,kA.y,kA.z,kA.w,kB.x,kB.y,kB.z,kB.w};
        float er[8] = {eA.x,eA.y,eA.z,eA.w,eB.x,eB.y,eB.z,eB.w};
        f32x2 p01 = (f32x2){0.f,0.f}, p23 = (f32x2){0.f,0.f};
        #pragma unroll
        for (int i = 0; i < 8; ++i) {
            const f32x2 kk = (f32x2){kr[i], kr[i]};
            const f32x2 ee = (f32x2){er[i], er[i]};
            const f32x2 qq = (f32x2){qr[i], qr[i]};
            S01[i] = S01[i] * ee + kk * v01;
            S23[i] = S23[i] * ee + kk * v23;
            p01 = p01 + qq * S01[i];
            p23 = p23 + qq * S23[i];
        }
        float p0 = dpp_red16(p01.x);
        float p1 = dpp_red16(p01.y);
        float p2 = dpp_red16(p23.x);
        float p3 = dpp_red16(p23.y);
        if (part == 0) *(float4*)op = make_float4(p0, p1, p2, p3);
        op += VDn;
    }
}

// ---------- RMSNorm + swish gate (g in bf16) -> bf16 ----------
__global__ __launch_bounds__(256) void rms_gate(const float* __restrict__ o,
    const ushort* __restrict__ gbf, const float* __restrict__ wt,
    ushort* __restrict__ obf)
{
    const int tid = threadIdx.x;
    const int w = tid >> 6, lane = tid & 63;
    const int row = blockIdx.x * 4 + w;     // n*H + h
    const int n = row >> 2, h = row & 3;
    const size_t ob_base = (size_t)n * VDn + h * DVn + lane * 4;

    float4 o4 = *(const float4*)&o[ob_base];
    float ss = o4.x*o4.x + o4.y*o4.y + o4.z*o4.z + o4.w*o4.w;
    #pragma unroll
    for (int m = 1; m < 64; m <<= 1) ss += __shfl_xor(ss, m);
    const float r = rsqrtf(ss * (1.0f / DVn) + 1e-5f);

    ushort4 gu = *(const ushort4*)&gbf[ob_base];
    float gx = __uint_as_float((unsigned)gu.x << 16);
    float gy = __uint_as_float((unsigned)gu.y << 16);
    float gz = __uint_as_float((unsigned)gu.z << 16);
    float gw = __uint_as_float((unsigned)gu.w << 16);
    float4 w4 = *(const float4*)&wt[h * DVn + lane * 4];
    ushort4 u;
    u.x = f2bf(o4.x * r * w4.x * (gx / (1.0f + expf(-gx))));
    u.y = f2bf(o4.y * r * w4.y * (gy / (1.0f + expf(-gy))));
    u.z = f2bf(o4.z * r * w4.z * (gz / (1.0f + expf(-gz))));
    u.w = f2bf(o4.w * r * w4.w * (gw / (1.0f + expf(-gw))));
    *(ushort4*)&obf[ob_base] = u;
}

extern "C" void kernel_launch(void* const* d_in, const int* in_sizes, int n_in,
                              void* d_out, int out_size, void* d_ws, size_t ws_size,
                              hipStream_t stream) {
    const float* hs          = (const float*)d_in[0];
    const float* Wq          = (const float*)d_in[1];
    const float* Wk          = (const float*)d_in[2];
    const float* Wv          = (const float*)d_in[3];
    const float* Wg          = (const float*)d_in[4];
    const float* Wa          = (const float*)d_in[5];
    const float* Wo          = (const float*)d_in[6];
    const float* A_log_base  = (const float*)d_in[7];
    const float* A_log_delta = (const float*)d_in[8];
    const float* dt_bias     = (const float*)d_in[9];
    const float* gnw         = (const float*)d_in[10];
    float* out = (float*)d_out;

    char* ws = (char*)d_ws;
    float*  qk   = (float*)(ws);                           // 32MB [8192][1024] q|k
    float*  vb   = (float*)(ws + ((size_t)32  << 20));     // 32MB [8192][1024] v fp32
    float*  Eb   = (float*)(ws + ((size_t)64  << 20));     // 16MB [8192][512]
    float*  Sl   = (float*)(ws + ((size_t)80  << 20));     // 64MB [32][16][128][256]
    float*  ob   = (float*)(ws + ((size_t)144 << 20));     // 32MB [8192][1024]
    ushort* hsb  = (ushort*)(ws + ((size_t)144 << 20));    // 16MB overlay on ob (dead before gla_out)
    ushort* gbf  = (ushort*)(ws + ((size_t)176 << 20));    // 16MB [8192][1024] g bf16
    ushort* Wqkab= (ushort*)(ws + ((size_t)192 << 20));    //  3MB [1536][1024] bf16
    ushort* Wvgb = (ushort*)(ws + ((size_t)195 << 20));    //  4MB [2048][1024] bf16
    ushort* Wob  = (ushort*)(ws + ((size_t)199 << 20));    //  2MB [1024][1024] bf16
    float*  Dc   = (float*)(ws + ((size_t)201 << 20));     // 256KB [32][16][128]
    ushort* obf  = (ushort*)qk;                            // reuse qk after gla_out

    // casts
    cast_f2b<<<NROWS * Dn / 4 / 256, 256, 0, stream>>>(hs, hsb, NROWS * Dn / 4);
    cast_f2b<<<512,  256, 0, stream>>>(Wq, Wqkab,              KDn * Dn / 4);
    cast_f2b<<<512,  256, 0, stream>>>(Wk, Wqkab + KDn * Dn,   KDn * Dn / 4);
    cast_f2b<<<512,  256, 0, stream>>>(Wa, Wqkab + 2*KDn * Dn, KDn * Dn / 4);
    cast_f2b<<<1024, 256, 0, stream>>>(Wv, Wvgb,               VDn * Dn / 4);
    cast_f2b<<<1024, 256, 0, stream>>>(Wg, Wvgb + VDn * Dn,    VDn * Dn / 4);
    cast_f2b<<<1024, 256, 0, stream>>>(Wo, Wob,                VDn * Dn / 4);

    // projections: q|k (scaled q) + fused gate transform -> Eb ; v fp32 + g bf16
    mm2<1,12><<<768,  256, 0, stream>>>(hsb, Wqkab, qk, nullptr, Eb,
                                        dt_bias, A_log_base, A_log_delta);
    mm2<2,16><<<1024, 256, 0, stream>>>(hsb, Wvgb, vb, gbf, nullptr,
                                        nullptr, nullptr, nullptr);

    // chunked recurrence: fine chunks for state (NC=32), coarse for output (16)
    gla_state<<<2048, 256, 0, stream>>>(qk, Eb, vb, Sl);
    decay_prod<<<dim3(NC, 16), 128, 0, stream>>>(Eb, Dc);
    combine<<<dim3(32, 16), 256, 0, stream>>>(Sl, Dc);
    gla_out<<<1024, 256, 0, stream>>>(qk, Eb, vb, Sl, ob);

    // epilogue
    rms_gate<<<NROWS * Hn / 4, 256, 0, stream>>>(ob, gbf, gnw, obf);
    mm2<0,8><<<512, 256, 0, stream>>>(obf, Wob, out, nullptr, nullptr,
                                      nullptr, nullptr, nullptr);
}